// Round 6
// baseline (164.465 us; speedup 1.0000x reference)
//
#include <hip/hip_runtime.h>
#include <stdint.h>

#define TB   256
#define TLEN 2048
#define NB   16
#define NCH  128
#define BN   (NB*NCH)   // 2048 rows
#define KP   6

typedef unsigned long long u64;

__device__ inline float2 cmul(float2 a, float2 b) {
  return make_float2(a.x * b.x - a.y * b.y, a.x * b.y + a.y * b.x);
}
__device__ inline float2 cadd(float2 a, float2 b) { return make_float2(a.x + b.x, a.y + b.y); }
__device__ inline float2 csub(float2 a, float2 b) { return make_float2(a.x - b.x, a.y - b.y); }
__device__ inline float2 cmni(float2 a) { return make_float2(a.y, -a.x); }  // *(-i)

#define PAD(o) ((o) + ((o) >> 4))
#define C2 0.70710678118654752f

// radix-8 butterfly with output twiddles (B[0] untwiddled); w1 = W^cb
__device__ inline void radix8(const float2 A[8], float2 w1, float2 B[8]) {
  float2 s02 = cadd(A[0], A[4]), d02 = csub(A[0], A[4]);
  float2 s13 = cadd(A[2], A[6]), d13 = csub(A[2], A[6]);
  float2 E0 = cadd(s02, s13), E1 = cadd(d02, cmni(d13));
  float2 E2 = csub(s02, s13), E3 = csub(d02, cmni(d13));
  float2 t02 = cadd(A[1], A[5]), e02 = csub(A[1], A[5]);
  float2 t13 = cadd(A[3], A[7]), e13 = csub(A[3], A[7]);
  float2 O0 = cadd(t02, t13), O1 = cadd(e02, cmni(e13));
  float2 O2 = csub(t02, t13), O3 = csub(e02, cmni(e13));
  float2 T0 = O0;
  float2 T1 = make_float2(C2 * (O1.x + O1.y), C2 * (O1.y - O1.x));
  float2 T2 = cmni(O2);
  float2 T3 = make_float2(C2 * (O3.y - O3.x), -C2 * (O3.x + O3.y));
  float2 b0 = cadd(E0, T0), b4 = csub(E0, T0);
  float2 b1 = cadd(E1, T1), b5 = csub(E1, T1);
  float2 b2 = cadd(E2, T2), b6 = csub(E2, T2);
  float2 b3 = cadd(E3, T3), b7 = csub(E3, T3);
  float2 w2 = cmul(w1, w1);
  float2 w3 = cmul(w2, w1);
  float2 w4 = cmul(w2, w2);
  float2 w5 = cmul(w4, w1);
  float2 w6 = cmul(w4, w2);
  float2 w7 = cmul(w4, w3);
  B[0] = b0;
  B[1] = cmul(w1, b1);
  B[2] = cmul(w2, b2);
  B[3] = cmul(w3, b3);
  B[4] = cmul(w4, b4);
  B[5] = cmul(w5, b5);
  B[6] = cmul(w6, b6);
  B[7] = cmul(w7, b7);
}

// ---------------------------------------------------------------------------
// K1: direct strided read of x + two-for-one real FFT (radix-8 x3 + radix-4)
//     + top-6 per row + fold into compact seg staging + params.
// rows 2r,2r+1 = channels (n, n+1) of batch b: one float2 per t.
// ---------------------------------------------------------------------------
__global__ __launch_bounds__(256) void k_fft_fold(const float* __restrict__ x,
                                                  float* __restrict__ seg,
                                                  int* __restrict__ Pg) {
  __shared__ __align__(16) float2 bufA[2176];   // 17.4 KB
  __shared__ __align__(16) float2 bufB[2176];   // 17.4 KB; spectrum ends here
  __shared__ float sraw[2][TLEN];               // 16 KB raw rows (FFT in + fold)
  __shared__ float2 tw[256];                    // 2 KB: W_2048^j
  __shared__ u64 wmax[4];
  __shared__ int4 prm[2][KP];
  int tid = threadIdx.x, lane = tid & 63, wv = tid >> 6;
  int r0 = blockIdx.x * 2;
  int b = r0 >> 7, n0 = r0 & 127;               // n0 even

  // strided load: x2[(b*2048+t)*64 + n0/2] = (x[b,t,n0], x[b,t,n0+1])
  const float2* x2 = (const float2*)x;
  size_t xoff = (size_t)b * TLEN * 64 + (n0 >> 1);
#pragma unroll
  for (int kk = 0; kk < 8; kk++) {
    int t = tid + kk * TB;
    float2 v = x2[xoff + (size_t)t * 64];
    sraw[0][t] = v.x;
    sraw[1][t] = v.y;
  }
  {
    float sn, cs;
    sincosf((-6.283185307179586f / 2048.f) * (float)tid, &sn, &cs);
    tw[tid] = make_float2(cs, sn);
  }
  __syncthreads();

  // stage 1 (s=1): read sraw, write bufA
  {
    int i = tid;
    float2 A[8], B[8];
#pragma unroll
    for (int j = 0; j < 8; j++)
      A[j] = make_float2(sraw[0][i + j * 256], sraw[1][i + j * 256]);
    radix8(A, tw[i], B);
    int o = 8 * i;
#pragma unroll
    for (int j = 0; j < 8; j++) bufA[PAD(o + j)] = B[j];
  }
  // stage 2 (s=8): bufA -> bufB ; stage 3 (s=64): bufB -> bufA
#pragma unroll
  for (int stage = 0; stage < 2; stage++) {
    int s = stage == 0 ? 8 : 64;
    float2* xb = stage == 0 ? bufA : bufB;
    float2* yb = stage == 0 ? bufB : bufA;
    __syncthreads();
    int i = tid;
    int q = i & (s - 1);
    int cb = i - q;
    float2 A[8], B[8];
#pragma unroll
    for (int j = 0; j < 8; j++) A[j] = xb[PAD(i + j * 256)];
    radix8(A, tw[cb], B);
    int o = q + 8 * cb;
#pragma unroll
    for (int j = 0; j < 8; j++) yb[PAD(o + j * s)] = B[j];
  }
  // final radix-4 (s=512, twiddle-free): bufA -> bufB
  __syncthreads();
#pragma unroll
  for (int ii = 0; ii < 2; ii++) {
    int i = tid + ii * TB;       // [0,512)
    float2 a0 = bufA[PAD(i)], a1 = bufA[PAD(i + 512)];
    float2 a2 = bufA[PAD(i + 1024)], a3 = bufA[PAD(i + 1536)];
    float2 S02 = cadd(a0, a2), D02 = csub(a0, a2);
    float2 S13 = cadd(a1, a3), D13 = csub(a1, a3);
    bufB[PAD(i)]        = cadd(S02, S13);
    bufB[PAD(i + 512)]  = cadd(D02, cmni(D13));
    bufB[PAD(i + 1024)] = csub(S02, S13);
    bufB[PAD(i + 1536)] = csub(D02, cmni(D13));
  }
  __syncthreads();

  const float2* Z = bufB;
  u64* keys = (u64*)bufA;        // [0..1023]=row r0, [1024..2047]=row r0+1
  for (int i = tid; i < 1024; i += TB) {
    int kb = i + 1;
    float2 zk = Z[PAD(kb)];
    float2 zc = Z[PAD(2048 - kb)];
    float ax = zk.x + zc.x, ay = zk.y - zc.y;   // 2*X[kb]
    float bx = zk.x - zc.x, by = zk.y + zc.y;   // 2i*Y[kb]
    float m2a = ax * ax + ay * ay;              // const scale, order-safe
    float m2b = bx * bx + by * by;
    keys[i]        = ((u64)__float_as_uint(m2a) << 32) | (unsigned)(0xFFFFFFFFu - (unsigned)kb);
    keys[1024 + i] = ((u64)__float_as_uint(m2b) << 32) | (unsigned)(0xFFFFFFFFu - (unsigned)kb);
  }
  __syncthreads();

  // top-6: waves 0-1 own row r0, waves 2-3 own row r0+1
  int rw2 = wv >> 1;
  u64* kb2 = keys + rw2 * 1024;
  int t2 = tid & 127;
  for (int r = 0; r < KP; r++) {
    u64 best = 0ull;
    for (int i = t2; i < 1024; i += 128) {
      u64 v = kb2[i];
      best = v > best ? v : best;
    }
    for (int off = 32; off > 0; off >>= 1) {
      u64 o = __shfl_down(best, off);
      best = o > best ? o : best;
    }
    if (lane == 0) wmax[wv] = best;
    __syncthreads();
    if (t2 == 0) {
      u64 b0 = wmax[rw2 * 2], b1 = wmax[rw2 * 2 + 1];
      best = b0 > b1 ? b0 : b1;
      int bin = (int)(0xFFFFFFFFu - (unsigned)(best & 0xFFFFFFFFull));
      if (bin < 1 || bin > 1024) bin = 1;
      kb2[bin - 1] = 0ull;
      int P = TLEN / bin;
      int cyc = TLEN / P;
      int base = TLEN - cyc * P;
      prm[rw2][r] = make_int4(P, base, cyc, 0);
      Pg[(r0 + rw2) * KP + r] = P;
    }
    __syncthreads();
  }

  // fold: 12 (row,k) tasks over 4 waves; write compact contiguous runs to seg
  for (int task = wv; task < 2 * KP; task += 4) {
    int rw = task & 1, k = task >> 1;
    int4 pr = prm[rw][k];
    int P = pr.x, base = pr.y, cyc = pr.z;
    float inv = 1.0f / (float)cyc;
    const float* srow = sraw[rw];
    float* dst = seg + ((size_t)(r0 + rw) * KP + k) * TLEN;

    if (P >= 64) {
      for (int p = lane; p < P; p += 64) {
        const float* sp = srow + base + p;
        float s = 0.f;
        for (int c = 0; c < cyc; c++) s += sp[c * P];
        dst[p] = s * inv;
      }
    } else {
      int wc = 64 / P, u = wc * P, ci = lane / P;
      float v = 0.f;
      if (lane < u) {
        for (int c0 = 0; c0 < cyc; c0 += wc) {
          int c = c0 + ci;
          if (c < cyc) v += srow[base + c0 * P + lane];
        }
      }
      for (int s = P; s < u; s <<= 1) {
        float o = __shfl_down(v, s);
        if (lane + s < u) v += o;
      }
      if (lane < P) dst[lane] = v * inv;
    }
  }
}

// ---------------------------------------------------------------------------
// K2: expand — write ALL of out (zeros + values) as coalesced float4 streams.
// block: bk = (b*KP+k), p-chunk of 128.  out[((b*KP+k)*TLEN+p)*NCH+n]
// ---------------------------------------------------------------------------
__global__ __launch_bounds__(256) void k_expand(const float* __restrict__ seg,
                                                const int* __restrict__ Pg,
                                                float4* __restrict__ out4) {
  __shared__ int Parr[NCH];
  int z = blockIdx.x;
  int pc = z & 15, bk = z >> 4;
  int b = bk / KP, k = bk - KP * b;
  int tid = threadIdx.x;
  if (tid < NCH) Parr[tid] = Pg[(b * NCH + tid) * KP + k];
  __syncthreads();
  int p0 = pc * 128;
  // 128 p x 32 float4 = 4096 float4 per block
  for (int e = tid; e < 4096; e += TB) {
    int p = p0 + (e >> 5);
    int n4 = (e & 31) * 4;
    float4 v = make_float4(0.f, 0.f, 0.f, 0.f);
    float* vp = &v.x;
#pragma unroll
    for (int c = 0; c < 4; c++) {
      int n = n4 + c;
      if (p < Parr[n])
        vp[c] = seg[((size_t)(b * NCH + n) * KP + k) * TLEN + p];
    }
    out4[((size_t)bk * TLEN + p) * (NCH / 4) + (e & 31)] = v;
  }
}

// ---------------------------------------------------------------------------
extern "C" void kernel_launch(void* const* d_in, const int* in_sizes, int n_in,
                              void* d_out, int out_size, void* d_ws, size_t ws_size,
                              hipStream_t stream) {
  const float* x = (const float*)d_in[0];
  float* out = (float*)d_out;
  char* ws = (char*)d_ws;

  const size_t seg_bytes = (size_t)BN * KP * TLEN * 4;   // 100.7 MB
  float* seg = (float*)ws;
  int* Pg = (int*)(ws + seg_bytes);                      // 48 KB

  k_fft_fold<<<BN / 2, 256, 0, stream>>>(x, seg, Pg);
  k_expand<<<NB * KP * 16, 256, 0, stream>>>(seg, Pg, (float4*)out);
}

// Round 7
// 144.211 us; speedup vs baseline: 1.1404x; 1.1404x over previous
//
#include <hip/hip_runtime.h>
#include <stdint.h>

#define TB   256
#define TLEN 2048
#define NB   16
#define NCH  128
#define BN   (NB*NCH)   // 2048 rows
#define KP   6

typedef unsigned long long u64;

__device__ inline float2 cmul(float2 a, float2 b) {
  return make_float2(a.x * b.x - a.y * b.y, a.x * b.y + a.y * b.x);
}
__device__ inline float2 cadd(float2 a, float2 b) { return make_float2(a.x + b.x, a.y + b.y); }
__device__ inline float2 csub(float2 a, float2 b) { return make_float2(a.x - b.x, a.y - b.y); }
__device__ inline float2 cmni(float2 a) { return make_float2(a.y, -a.x); }  // *(-i)

#define PAD(o) ((o) + ((o) >> 4))
#define C2 0.70710678118654752f

// radix-8 butterfly with output twiddles (B[0] untwiddled); w1 = W^cb
__device__ inline void radix8(const float2 A[8], float2 w1, float2 B[8]) {
  float2 s02 = cadd(A[0], A[4]), d02 = csub(A[0], A[4]);
  float2 s13 = cadd(A[2], A[6]), d13 = csub(A[2], A[6]);
  float2 E0 = cadd(s02, s13), E1 = cadd(d02, cmni(d13));
  float2 E2 = csub(s02, s13), E3 = csub(d02, cmni(d13));
  float2 t02 = cadd(A[1], A[5]), e02 = csub(A[1], A[5]);
  float2 t13 = cadd(A[3], A[7]), e13 = csub(A[3], A[7]);
  float2 O0 = cadd(t02, t13), O1 = cadd(e02, cmni(e13));
  float2 O2 = csub(t02, t13), O3 = csub(e02, cmni(e13));
  float2 T0 = O0;
  float2 T1 = make_float2(C2 * (O1.x + O1.y), C2 * (O1.y - O1.x));
  float2 T2 = cmni(O2);
  float2 T3 = make_float2(C2 * (O3.y - O3.x), -C2 * (O3.x + O3.y));
  float2 b0 = cadd(E0, T0), b4 = csub(E0, T0);
  float2 b1 = cadd(E1, T1), b5 = csub(E1, T1);
  float2 b2 = cadd(E2, T2), b6 = csub(E2, T2);
  float2 b3 = cadd(E3, T3), b7 = csub(E3, T3);
  float2 w2 = cmul(w1, w1);
  float2 w3 = cmul(w2, w1);
  float2 w4 = cmul(w2, w2);
  float2 w5 = cmul(w4, w1);
  float2 w6 = cmul(w4, w2);
  float2 w7 = cmul(w4, w3);
  B[0] = b0;
  B[1] = cmul(w1, b1);
  B[2] = cmul(w2, b2);
  B[3] = cmul(w3, b3);
  B[4] = cmul(w4, b4);
  B[5] = cmul(w5, b5);
  B[6] = cmul(w6, b6);
  B[7] = cmul(w7, b7);
}

// ---------------------------------------------------------------------------
// K0: fused zero-fill(out) + transpose x[b][t][n] -> seqs[(b*NCH+n)][t]
// blocks [0,1024): transpose tiles; blocks [1024, ...): fill out
// ---------------------------------------------------------------------------
__global__ __launch_bounds__(256) void k_prep(const float* __restrict__ x,
                                              float* __restrict__ seqs,
                                              float4* __restrict__ out4, int n4) {
  int bid = blockIdx.x;
  if (bid < 1024) {
    __shared__ float tile[64][65];
    int tb = bid & 31, nb = (bid >> 5) & 1, b = bid >> 6;
    int t0 = tb * 64, n0 = nb * 64;
    int tx = threadIdx.x & 63, ty = threadIdx.x >> 6;
#pragma unroll
    for (int tt = ty; tt < 64; tt += 4)
      tile[tt][tx] = x[(size_t)(b * TLEN + t0 + tt) * NCH + n0 + tx];
    __syncthreads();
#pragma unroll
    for (int nn = ty; nn < 64; nn += 4)
      seqs[(size_t)(b * NCH + n0 + nn) * TLEN + t0 + tx] = tile[tx][nn];
  } else {
    int i = (bid - 1024) * 256 + threadIdx.x;
    if (i < n4) out4[i] = make_float4(0.f, 0.f, 0.f, 0.f);
  }
}

// ---------------------------------------------------------------------------
// K1: two-for-one real FFT (radix-8 x3 + radix-4, Stockham, padded LDS)
//     + register-resident per-wave top-6 + fold, scatter-written to out.
// LDS: bufA 17.4K + bufB 17.4K + tw 2K  => ~37 KB -> 4 blocks/CU.
// ---------------------------------------------------------------------------
__global__ __launch_bounds__(256) void k_fft_fold(const float* __restrict__ seqs,
                                                  float* __restrict__ out) {
  __shared__ __align__(16) float2 bufA[2176];   // spectrum ends here
  __shared__ __align__(16) float2 bufB[2176];   // raw rows reloaded here post-FFT
  __shared__ float2 tw[256];                    // W_2048^j, j<256
  __shared__ int4 prm[2][KP];
  int tid = threadIdx.x, lane = tid & 63, wv = tid >> 6;
  int r0 = blockIdx.x * 2;
  const float* row0 = seqs + (size_t)r0 * TLEN;

  // load rows 2r, 2r+1 as (re, im) — coalesced from seqs
#pragma unroll
  for (int kk = 0; kk < 8; kk++) {
    int t = tid + kk * TB;
    bufA[PAD(t)] = make_float2(row0[t], row0[t + TLEN]);
  }
  {
    float sn, cs;
    sincosf((-6.283185307179586f / 2048.f) * (float)tid, &sn, &cs);
    tw[tid & 255] = make_float2(cs, sn);
  }

  // 3 radix-8 stages: s=1 (A->B), s=8 (B->A), s=64 (A->B)
#pragma unroll
  for (int stage = 0; stage < 3; stage++) {
    int s = (stage == 0) ? 1 : (stage == 1) ? 8 : 64;
    float2* xb = (stage == 1) ? bufB : bufA;
    float2* yb = (stage == 1) ? bufA : bufB;
    __syncthreads();
    int i = tid;
    int q = i & (s - 1);
    int cb = i - q;
    float2 A[8], B[8];
#pragma unroll
    for (int j = 0; j < 8; j++) A[j] = xb[PAD(i + j * 256)];
    radix8(A, tw[cb], B);
    int o = q + 8 * cb;
#pragma unroll
    for (int j = 0; j < 8; j++) yb[PAD(o + j * s)] = B[j];
  }
  // final radix-4 (s=512, twiddle-free): B -> A ; spectrum lands in bufA
  __syncthreads();
#pragma unroll
  for (int ii = 0; ii < 2; ii++) {
    int i = tid + ii * TB;       // [0,512)
    float2 a0 = bufB[PAD(i)], a1 = bufB[PAD(i + 512)];
    float2 a2 = bufB[PAD(i + 1024)], a3 = bufB[PAD(i + 1536)];
    float2 S02 = cadd(a0, a2), D02 = csub(a0, a2);
    float2 S13 = cadd(a1, a3), D13 = csub(a1, a3);
    bufA[PAD(i)]        = cadd(S02, S13);
    bufA[PAD(i + 512)]  = cadd(D02, cmni(D13));
    bufA[PAD(i + 1024)] = csub(S02, S13);
    bufA[PAD(i + 1536)] = csub(D02, cmni(D13));
  }
  __syncthreads();

  const float2* Z = bufA;
  float* srows = (float*)bufB;   // bufB dead after final stage

  if (wv < 2) {
    // wave wv owns row r0+wv: 16 keys per lane, all-register top-6
    u64 kr[16];
#pragma unroll
    for (int j = 0; j < 16; j++) {
      int kb = lane * 16 + j + 1;          // bins 1..1024
      float2 zk = Z[PAD(kb)];
      float2 zc = Z[PAD(2048 - kb)];
      float m2;
      if (wv == 0) {
        float ax = zk.x + zc.x, ay = zk.y - zc.y;   // 2*X[kb]
        m2 = ax * ax + ay * ay;                     // const scale, order-safe
      } else {
        float bx = zk.x - zc.x, by = zk.y + zc.y;   // 2i*Y[kb]
        m2 = bx * bx + by * by;
      }
      kr[j] = ((u64)__float_as_uint(m2) << 32) | (unsigned)(0xFFFFFFFFu - (unsigned)kb);
    }
#pragma unroll 1
    for (int r = 0; r < KP; r++) {
      u64 m = kr[0];
#pragma unroll
      for (int j = 1; j < 16; j++) m = kr[j] > m ? kr[j] : m;
#pragma unroll
      for (int off = 1; off < 64; off <<= 1) {
        u64 o = __shfl_xor(m, off);
        m = o > m ? o : m;
      }
#pragma unroll
      for (int j = 0; j < 16; j++)
        if (kr[j] == m) kr[j] = 0ull;      // keys unique (bin embedded)
      if (lane == 0) {
        int bin = (int)(0xFFFFFFFFu - (unsigned)(m & 0xFFFFFFFFull));
        if (bin < 1 || bin > 1024) bin = 1;
        int P = TLEN / bin;
        int cyc = TLEN / P;
        int base = TLEN - cyc * P;
        prm[wv][r] = make_int4(P, base, cyc, 0);
      }
    }
  } else {
    // waves 2,3: reload raw rows (L2-hot) into dead bufB
    const float4* s4 = (const float4*)row0;
    float4* r4 = (float4*)srows;
    for (int i = tid - 128; i < 1024; i += 128) r4[i] = s4[i];
  }
  __syncthreads();   // prm visible, srows loaded

  // fold: 12 (row,k) tasks over 4 waves; scatter into pre-zeroed out
  for (int task = wv; task < 2 * KP; task += 4) {
    int rw = task & 1, k = task >> 1;
    int4 pr = prm[rw][k];
    int P = pr.x, base = pr.y, cyc = pr.z;
    float inv = 1.0f / (float)cyc;
    const float* srow = srows + rw * TLEN;
    int row = r0 + rw, b = row >> 7, n = row & 127;
    float* dst = out + (size_t)(b * KP + k) * TLEN * NCH + n;

    if (P >= 64) {
      for (int p = lane; p < P; p += 64) {
        const float* sp = srow + base + p;
        float s = 0.f;
        for (int c = 0; c < cyc; c++) s += sp[c * P];
        dst[(size_t)p * NCH] = s * inv;
      }
    } else {
      int wc = 64 / P, u = wc * P, ci = lane / P;
      float v = 0.f;
      if (lane < u) {
        for (int c0 = 0; c0 < cyc; c0 += wc) {
          int c = c0 + ci;
          if (c < cyc) v += srow[base + c0 * P + lane];
        }
      }
      for (int s = P; s < u; s <<= 1) {
        float o = __shfl_down(v, s);
        if (lane + s < u) v += o;
      }
      if (lane < P) dst[(size_t)lane * NCH] = v * inv;
    }
  }
}

// ---------------------------------------------------------------------------
extern "C" void kernel_launch(void* const* d_in, const int* in_sizes, int n_in,
                              void* d_out, int out_size, void* d_ws, size_t ws_size,
                              hipStream_t stream) {
  const float* x = (const float*)d_in[0];
  float* out = (float*)d_out;
  float* seqs = (float*)d_ws;                    // 16.8 MB

  int n4 = out_size / 4;
  int fill_blocks = (n4 + 255) / 256;
  k_prep<<<1024 + fill_blocks, 256, 0, stream>>>(x, seqs, (float4*)out, n4);
  k_fft_fold<<<BN / 2, 256, 0, stream>>>(seqs, out);
}